// Round 6
// baseline (203.278 us; speedup 1.0000x reference)
//
#include <hip/hip_runtime.h>

// WaveletTransform: Haar 2x2 on (8, 64, 512, 512) fp32 -> 4x (8, 64, 256, 256) fp32
// Memory-bound single pass. Per thread: 8 input cols x 2 rows (4x 16B cached loads)
// -> 4 output pixels per subband (4x 16B cached stores).
// R6: R5 with nontemporal removed from stores (A/B: cached stores write-combine in L2;
// fill kernels with plain stores hit 6.7 TB/s vs our 5.45 with nt).

#define BB 8
#define CC 64
#define HH_ 512
#define WW_ 512
#define OUTH (HH_ / 2)
#define OUTW (WW_ / 2)

typedef float v4f __attribute__((ext_vector_type(4)));

__global__ __launch_bounds__(256) void haar2x2_kernel(
    const float* __restrict__ x, float* __restrict__ out, int total)
{
    // per-image work: OUTH row-pairs * (WW_/8) octs = 256 * 64 = 16384 = 2^14
    const size_t subband = (size_t)BB * CC * OUTH * OUTW;  // 33554432

    int idx = blockIdx.x * blockDim.x + threadIdx.x;
    int stride = gridDim.x * blockDim.x;

    for (int t = idx; t < total; t += stride) {
        int img = t >> 14;
        int rem = t & 16383;
        int ho  = rem >> 6;       // output row, 0..255
        int wo  = rem & 63;       // 8-column group index within the input row

        const float* rowbase = x + (size_t)img * HH_ * WW_ + (size_t)(2 * ho) * WW_;
        const v4f* r0p = reinterpret_cast<const v4f*>(rowbase) + wo * 2;
        const v4f* r1p = reinterpret_cast<const v4f*>(rowbase + WW_) + wo * 2;

        v4f r0a = r0p[0];   // a0 b0 a1 b1
        v4f r0b = r0p[1];   // a2 b2 a3 b3
        v4f r1a = r1p[0];   // c0 d0 c1 d1
        v4f r1b = r1p[1];   // c2 d2 c3 d3

        v4f ll, lh, hl, hh;

        // pixel 0
        {
            float s0 = r0a.x + r0a.y, d0 = r0a.x - r0a.y;
            float s1 = r1a.x + r1a.y, d1 = r1a.x - r1a.y;
            ll.x = (s0 + s1) * 0.5f; lh.x = (s0 - s1) * 0.5f;
            hl.x = (d0 + d1) * 0.5f; hh.x = (d0 - d1) * 0.5f;
        }
        // pixel 1
        {
            float s0 = r0a.z + r0a.w, d0 = r0a.z - r0a.w;
            float s1 = r1a.z + r1a.w, d1 = r1a.z - r1a.w;
            ll.y = (s0 + s1) * 0.5f; lh.y = (s0 - s1) * 0.5f;
            hl.y = (d0 + d1) * 0.5f; hh.y = (d0 - d1) * 0.5f;
        }
        // pixel 2
        {
            float s0 = r0b.x + r0b.y, d0 = r0b.x - r0b.y;
            float s1 = r1b.x + r1b.y, d1 = r1b.x - r1b.y;
            ll.z = (s0 + s1) * 0.5f; lh.z = (s0 - s1) * 0.5f;
            hl.z = (d0 + d1) * 0.5f; hh.z = (d0 - d1) * 0.5f;
        }
        // pixel 3
        {
            float s0 = r0b.z + r0b.w, d0 = r0b.z - r0b.w;
            float s1 = r1b.z + r1b.w, d1 = r1b.z - r1b.w;
            ll.w = (s0 + s1) * 0.5f; lh.w = (s0 - s1) * 0.5f;
            hl.w = (d0 + d1) * 0.5f; hh.w = (d0 - d1) * 0.5f;
        }

        size_t obase = (size_t)img * OUTH * OUTW + (size_t)ho * OUTW + (size_t)(wo * 4);
        *reinterpret_cast<v4f*>(out + 0 * subband + obase) = ll;
        *reinterpret_cast<v4f*>(out + 1 * subband + obase) = lh;
        *reinterpret_cast<v4f*>(out + 2 * subband + obase) = hl;
        *reinterpret_cast<v4f*>(out + 3 * subband + obase) = hh;
    }
}

extern "C" void kernel_launch(void* const* d_in, const int* in_sizes, int n_in,
                              void* d_out, int out_size, void* d_ws, size_t ws_size,
                              hipStream_t stream) {
    const float* x = (const float*)d_in[0];
    float* out = (float*)d_out;

    const int total = BB * CC * OUTH * (WW_ / 8);  // 8,388,608 work items
    const int block = 256;
    const int grid = 2048;

    haar2x2_kernel<<<grid, block, 0, stream>>>(x, out, total);
}

// Round 7
// 197.192 us; speedup vs baseline: 1.0309x; 1.0309x over previous
//
#include <hip/hip_runtime.h>

// WaveletTransform: Haar 2x2 on (8, 64, 512, 512) fp32 -> 4x (8, 64, 256, 256) fp32
// R7: wave-cooperative row-pair mapping — perfectly contiguous 16B/lane loads AND
// stores; lane^1 DPP shuffle repacks outputs into float4 stores.
// Cached loads + nontemporal stores (best combo from R3/R5/R6 A/B).

#define BB 8
#define CC 64
#define HH_ 512
#define WW_ 512
#define OUTH (HH_ / 2)
#define OUTW (WW_ / 2)

#define NWAVES 8192            // 2048 blocks * 4 waves
#define ITEMS 16               // 131072 row-pair items / 8192 waves

typedef float v4f __attribute__((ext_vector_type(4)));

struct H2 { float ux, uy; };   // two output pixels of one subband, one half-row

__global__ __launch_bounds__(256) void haar2x2_kernel(
    const float* __restrict__ x, float* __restrict__ out)
{
    const size_t subband = (size_t)BB * CC * OUTH * OUTW;  // 33554432

    const int wave = (blockIdx.x * blockDim.x + threadIdx.x) >> 6;
    const int lane = threadIdx.x & 63;
    const bool odd = (lane & 1) != 0;
    const int coloff = ((lane & ~1) << 1) + (odd ? 128 : 0);  // store col for this lane

    for (int k = 0; k < ITEMS; ++k) {
        int item = wave + k * NWAVES;       // row-pair index, 0..131071
        int img  = item >> 8;               // image (B*C), 0..511
        int ho   = item & 255;              // output row, 0..255

        const float* rb = x + (size_t)img * (HH_ * WW_) + (size_t)(2 * ho) * WW_;
        const v4f* p = reinterpret_cast<const v4f*>(rb);

        v4f A0 = p[lane];           // row0, cols [4l, 4l+4)        (half0)
        v4f A1 = p[64 + lane];      // row0, cols [256+4l, ...)     (half1)
        v4f B0 = p[128 + lane];     // row1, half0
        v4f B1 = p[192 + lane];     // row1, half1

        // haar per half: u_* from (A0,B0), v_* from (A1,B1); 2 px each
        float2 u_ll, u_lh, u_hl, u_hh, v_ll, v_lh, v_hl, v_hh;
        {
            float s0 = A0.x + A0.y, d0 = A0.x - A0.y;
            float s1 = B0.x + B0.y, d1 = B0.x - B0.y;
            u_ll.x = (s0 + s1) * 0.5f; u_lh.x = (s0 - s1) * 0.5f;
            u_hl.x = (d0 + d1) * 0.5f; u_hh.x = (d0 - d1) * 0.5f;
            s0 = A0.z + A0.w; d0 = A0.z - A0.w;
            s1 = B0.z + B0.w; d1 = B0.z - B0.w;
            u_ll.y = (s0 + s1) * 0.5f; u_lh.y = (s0 - s1) * 0.5f;
            u_hl.y = (d0 + d1) * 0.5f; u_hh.y = (d0 - d1) * 0.5f;
        }
        {
            float s0 = A1.x + A1.y, d0 = A1.x - A1.y;
            float s1 = B1.x + B1.y, d1 = B1.x - B1.y;
            v_ll.x = (s0 + s1) * 0.5f; v_lh.x = (s0 - s1) * 0.5f;
            v_hl.x = (d0 + d1) * 0.5f; v_hh.x = (d0 - d1) * 0.5f;
            s0 = A1.z + A1.w; d0 = A1.z - A1.w;
            s1 = B1.z + B1.w; d1 = B1.z - B1.w;
            v_ll.y = (s0 + s1) * 0.5f; v_lh.y = (s0 - s1) * 0.5f;
            v_hl.y = (d0 + d1) * 0.5f; v_hh.y = (d0 - d1) * 0.5f;
        }

        size_t obase = (size_t)img * (OUTH * OUTW) + (size_t)ho * OUTW + coloff;
        float* o0 = out + 0 * subband + obase;
        float* o1 = out + 1 * subband + obase;
        float* o2 = out + 2 * subband + obase;
        float* o3 = out + 3 * subband + obase;

        // per subband: odd lanes send u (half0), even lanes send v (half1);
        // lane^1 exchange; even stores (u, r) at cols 4j.., odd stores (r, v) at 128+4j..
        #define EMIT(U, V, DST)                                            \
        {                                                                  \
            float sx = odd ? U.x : V.x;                                    \
            float sy = odd ? U.y : V.y;                                    \
            float rx = __shfl_xor(sx, 1, 64);                              \
            float ry = __shfl_xor(sy, 1, 64);                              \
            v4f o;                                                         \
            o.x = odd ? rx : U.x;                                          \
            o.y = odd ? ry : U.y;                                          \
            o.z = odd ? V.x : rx;                                          \
            o.w = odd ? V.y : ry;                                          \
            __builtin_nontemporal_store(o, reinterpret_cast<v4f*>(DST));   \
        }

        EMIT(u_ll, v_ll, o0);
        EMIT(u_lh, v_lh, o1);
        EMIT(u_hl, v_hl, o2);
        EMIT(u_hh, v_hh, o3);
        #undef EMIT
    }
}

extern "C" void kernel_launch(void* const* d_in, const int* in_sizes, int n_in,
                              void* d_out, int out_size, void* d_ws, size_t ws_size,
                              hipStream_t stream) {
    const float* x = (const float*)d_in[0];
    float* out = (float*)d_out;

    haar2x2_kernel<<<2048, 256, 0, stream>>>(x, out);
}